// Round 5
// baseline (130.063 us; speedup 1.0000x reference)
//
#include <hip/hip_runtime.h>

// ConvCaps EM-routing, MI355X. 392 independent problems, one 512-thread block each.
// Thread = (o = t&31 out-cap, kc = t>>5 of 16 k-chunks, 18 k each).
// Fused E+M (3 vote passes total). Inner math on float2 ext-vectors to hit
// gfx950 packed-fp32 (v_pk_fma_f32) dual-issue. Softmax over o via half-wave
// shuffles; kk loop unrolled x2 to interleave the serial shuffle chains.

namespace {

constexpr int NKK = 288;
constexpr float EPSF = 1e-8f;
constexpr float LN2PI = 1.8378770664093453f;

typedef float v2f __attribute__((ext_vector_type(2)));

__device__ __forceinline__ float fastrcp(float x) { return __builtin_amdgcn_rcpf(x); }

__global__ __launch_bounds__(512, 4)
void caps_em_kernel(const float* __restrict__ x,
                    const float* __restrict__ Wg,
                    const float* __restrict__ bu,
                    const float* __restrict__ ba,
                    float* __restrict__ out)
{
    // LDS: 18432 + 1152 + 33792 + 2304 + 2304 + 128 + 128 = 58240 B -> 2 blocks/CU
    __shared__ float p4[NKK * 16];       // pose fragments [k*16+p]
    __shared__ float cIn[NKK];           // a/(a+eps)
    __shared__ float scr[8 * 32 * 33];   // [g][o][ Sv(16) | Sv2(16) | S0 ]
    __shared__ float meanS[32 * 18];     // mean[o*18+p]  (even stride: b64-aligned)
    __shared__ float i2vS[32 * 18];      // 1/(2*std^2)
    __shared__ float actS[32];
    __shared__ float baseS[32];          // log(act) - sum_p log std - 8*ln2pi

    const int n = blockIdx.x;
    const int t = threadIdx.x;

    // ---- gather poses: flat view of tiled (B,kh,kw,oh,ow,512) ----
    for (int idx = t; idx < NKK * 16; idx += 512) {
        unsigned g = (unsigned)n * 4608u + (unsigned)idx;
        unsigned c = g & 511u, rest = g >> 9;
        unsigned ow = rest % 7u; rest /= 7u;
        unsigned oh = rest % 7u; rest /= 7u;
        unsigned kw = rest % 3u; rest /= 3u;
        unsigned kh = rest % 3u;
        unsigned b  = rest / 3u;
        p4[idx] = x[((b*16u + 2u*oh + kh)*16u + 2u*ow + kw)*544u + c];
    }
    // ---- gather acts -> c_k ----
    for (int idx = t; idx < NKK; idx += 512) {
        unsigned g = (unsigned)n * 288u + (unsigned)idx;
        unsigned c = g & 31u, rest = g >> 5;
        unsigned ow = rest % 7u; rest /= 7u;
        unsigned oh = rest % 7u; rest /= 7u;
        unsigned kw = rest % 3u; rest /= 3u;
        unsigned kh = rest % 3u;
        unsigned b  = rest / 3u;
        const float a = x[((b*16u + 2u*oh + kh)*16u + 2u*ow + kw)*544u + 512u + c];
        cIn[idx] = a / (a + EPSF);
    }
    __syncthreads();

    const int o  = t & 31;    // out-cap (== lane&31)
    const int kc = t >> 5;    // k-chunk 0..15 (18 k each)
    const int oo = t >> 4;    // stats row 0..31
    const int pp = t & 15;    // stats col 0..15

    float lam = 1.0e-3f;

    for (int it = 0; it < 3; ++it) {
        lam += 1.0e-4f;

        float S0 = 0.f;
        v2f Sv[8], Sq[8];
        #pragma unroll
        for (int q = 0; q < 8; ++q) { Sv[q] = (v2f)(0.f); Sq[q] = (v2f)(0.f); }

        if (it == 0) {
            // ---- M0: uniform r -> u_k = c_k/32 (same for all o) ----
            #pragma unroll 2
            for (int kk = 0; kk < 18; ++kk) {
                const int k = kc*18 + kk;
                const float w = cIn[k] * 0.03125f;
                float P[16]; v2f W2[8];
                #pragma unroll
                for (int j = 0; j < 4; ++j) {
                    const float4 v4 = *(const float4*)&p4[k*16 + j*4];
                    P[j*4] = v4.x; P[j*4+1] = v4.y; P[j*4+2] = v4.z; P[j*4+3] = v4.w;
                    const float4 w4 = *(const float4*)&Wg[(k*32 + o)*16 + j*4];
                    W2[j*2]   = (v2f){w4.x, w4.y};
                    W2[j*2+1] = (v2f){w4.z, w4.w};
                }
                S0 += w;
                #pragma unroll
                for (int i = 0; i < 4; ++i) {
                    #pragma unroll
                    for (int m2 = 0; m2 < 2; ++m2) {
                        v2f v = P[i*4] * W2[m2];
                        v += P[i*4+1] * W2[2+m2];
                        v += P[i*4+2] * W2[4+m2];
                        v += P[i*4+3] * W2[6+m2];
                        const v2f wv = v * w;
                        Sv[i*2+m2] += wv;
                        Sq[i*2+m2] += wv * v;
                    }
                }
            }
        } else {
            // ---- fused E(prev stats) + M accumulate ----
            v2f M2[8], I2[8];
            #pragma unroll
            for (int q = 0; q < 8; ++q) {
                M2[q] = *(const v2f*)&meanS[o*18 + q*2];
                I2[q] = *(const v2f*)&i2vS [o*18 + q*2];
            }
            const float base = baseS[o];
            #pragma unroll 2
            for (int kk = 0; kk < 18; ++kk) {
                const int k = kc*18 + kk;
                float P[16]; v2f W2[8];
                #pragma unroll
                for (int j = 0; j < 4; ++j) {
                    const float4 v4 = *(const float4*)&p4[k*16 + j*4];
                    P[j*4] = v4.x; P[j*4+1] = v4.y; P[j*4+2] = v4.z; P[j*4+3] = v4.w;
                    const float4 w4 = *(const float4*)&Wg[(k*32 + o)*16 + j*4];
                    W2[j*2]   = (v2f){w4.x, w4.y};
                    W2[j*2+1] = (v2f){w4.z, w4.w};
                }
                v2f vt[8];
                v2f sacc2 = (v2f)(0.f);
                #pragma unroll
                for (int i = 0; i < 4; ++i) {
                    #pragma unroll
                    for (int m2 = 0; m2 < 2; ++m2) {
                        v2f v = P[i*4] * W2[m2];
                        v += P[i*4+1] * W2[2+m2];
                        v += P[i*4+2] * W2[4+m2];
                        v += P[i*4+3] * W2[6+m2];
                        vt[i*2+m2] = v;
                        const v2f d = v - M2[i*2+m2];
                        sacc2 += (d * I2[i*2+m2]) * d;
                    }
                }
                const float lnp = base - (sacc2.x + sacc2.y);
                // softmax over the 32 o's in this half-wave
                float mx = lnp;
                #pragma unroll
                for (int d = 1; d < 32; d <<= 1) mx = fmaxf(mx, __shfl_xor(mx, d, 64));
                const float e = __expf(lnp - mx);
                float ss = e;
                #pragma unroll
                for (int d = 1; d < 32; d <<= 1) ss += __shfl_xor(ss, d, 64);
                const float u = e * fastrcp(ss) * cIn[k];
                S0 += u;
                #pragma unroll
                for (int q = 0; q < 8; ++q) {
                    const v2f uv = vt[q] * u;
                    Sv[q] += uv;
                    Sq[q] += uv * vt[q];
                }
            }
        }

        // ---- combine kc pairs (partner lane^32, same wave) -> 8 groups ----
        S0 += __shfl_xor(S0, 32, 64);
        #pragma unroll
        for (int q = 0; q < 8; ++q) {
            Sv[q].x += __shfl_xor(Sv[q].x, 32, 64);
            Sv[q].y += __shfl_xor(Sv[q].y, 32, 64);
            Sq[q].x += __shfl_xor(Sq[q].x, 32, 64);
            Sq[q].y += __shfl_xor(Sq[q].y, 32, 64);
        }
        if ((kc & 1) == 0) {
            float* row = &scr[((kc >> 1)*32 + o)*33];
            #pragma unroll
            for (int q = 0; q < 8; ++q) {
                row[q*2]      = Sv[q].x; row[q*2+1]      = Sv[q].y;
                row[16 + q*2] = Sq[q].x; row[16 + q*2+1] = Sq[q].y;
            }
            row[32] = S0;
        }
        __syncthreads();

        // ---- reduce 8 groups + stats + activation; thread t = (oo, pp) ----
        {
            float sm = 0.f, s2 = 0.f, rs = 0.f;
            #pragma unroll
            for (int q = 0; q < 8; ++q) {
                const int b0 = (q*32 + oo)*33;
                sm += scr[b0 + pp];
                s2 += scr[b0 + 16 + pp];
                rs += scr[b0 + 32];
            }
            const float inv = 1.0f / (rs + EPSF);
            const float S1  = rs * inv;
            const float m   = sm * inv;
            float var = s2 * inv - m*m*(2.0f - S1);
            var = fmaxf(var, 0.0f) + EPSF;          // std^2 (+eps inside sqrt)
            meanS[oo*18 + pp] = m;
            i2vS [oo*18 + pp] = 0.5f / var;
            // lsum = sum_p log(std) via 16-lane shuffle reduce
            float ls = 0.5f * __logf(var);
            #pragma unroll
            for (int d = 1; d < 16; d <<= 1) ls += __shfl_xor(ls, d, 64);
            if (pp == 0) {
                const float cost = (16.0f * bu[oo] + ls) * rs;
                const float ao   = 1.0f / (1.0f + __expf(-lam * (ba[oo] - cost)));
                actS[oo]  = ao;
                baseS[oo] = -ls - 8.0f*LN2PI + __logf(ao);
            }
        }
        __syncthreads();
    }

    // ---- output: [mean(512) | act(32)] per n ----
    for (int idx = t; idx < 544; idx += 512) {
        const float v = (idx < 512) ? meanS[(idx >> 4)*18 + (idx & 15)]
                                    : actS[idx - 512];
        out[n*544 + idx] = v;
    }
}

} // namespace

extern "C" void kernel_launch(void* const* d_in, const int* in_sizes, int n_in,
                              void* d_out, int out_size, void* d_ws, size_t ws_size,
                              hipStream_t stream) {
    (void)in_sizes; (void)n_in; (void)out_size; (void)d_ws; (void)ws_size;
    const float* x  = (const float*)d_in[0];
    const float* W  = (const float*)d_in[1];
    const float* bu = (const float*)d_in[2];
    const float* ba = (const float*)d_in[3];
    float* out = (float*)d_out;
    caps_em_kernel<<<dim3(392), dim3(512), 0, stream>>>(x, W, bu, ba, out);
}